// Round 1
// baseline (129.828 us; speedup 1.0000x reference)
//
#include <hip/hip_runtime.h>

#define SS 2048
#define NN_ 32
#define HH 512
#define EE 256
#define TWO_H 1024

// d_out offsets (floats): predictions[32,10], hidden_new[2,32,512], cell_new[2,32,512]
#define OUT_PRED 0
#define OUT_H0 320
#define OUT_H1 16704
#define OUT_C0 33088
#define OUT_C1 49472

// workspace offsets (floats)
#define WS_ACC 0            // [1024 blocks][1024]  (attention partials)
#define WS_SUMW 1048576     // [1024]
#define WS_XCAT0 1049600    // [1792][32]  xcat0^T: rows 0..1023 ctx, 1024..1279 emb, 1280..1791 hidden[0]^T
// regions below reuse WS_ACC space (attention partials dead after reduce_ctx)
#define WS_GA0 0            // [2048][32]
#define WS_GB0 65536        // [2048][32]
#define WS_XCAT1 131072     // [1024][32]  rows 0..511 h0^T, 512..1023 hidden[1]^T
#define WS_GA1 163840       // [2048][32]
#define WS_GB1 229376       // [2048][32]

__device__ __forceinline__ float wave_reduce(float v) {
  v += __shfl_xor(v, 32);
  v += __shfl_xor(v, 16);
  v += __shfl_xor(v, 8);
  v += __shfl_xor(v, 4);
  v += __shfl_xor(v, 2);
  v += __shfl_xor(v, 1);
  return v;
}

__device__ __forceinline__ float sigmoidf_(float x) { return 1.0f / (1.0f + __expf(-x)); }

// ---------------- K2: fused energy + online softmax-weighted context accumulation ----------------
// grid: 1024 blocks (n in [0,32) x chunk in [0,32)); block: 256 thr = 4 waves; each wave: 16 s-rows.
__global__ __launch_bounds__(256, 4) void attn_pass(
    const float* __restrict__ enc, const float* __restrict__ hidden,
    const float* __restrict__ We, const float* __restrict__ be,
    float* __restrict__ ws) {
  const int blk = blockIdx.x;
  const int n = blk >> 5;
  const int chunk = blk & 31;
  const int t = threadIdx.x;
  const int wave = t >> 6;
  const int lane = t & 63;

  // c_n = dot(hidden[1][n], We[0:512]) + b  (computed redundantly per wave; 2KB from L2)
  const float* hl = hidden + (size_t)(NN_ + n) * HH;
  float cp;
  {
    float4 a = *(const float4*)(hl + lane * 8);
    float4 b = *(const float4*)(hl + lane * 8 + 4);
    float4 wa = *(const float4*)(We + lane * 8);
    float4 wb = *(const float4*)(We + lane * 8 + 4);
    cp = a.x * wa.x + a.y * wa.y + a.z * wa.z + a.w * wa.w +
         b.x * wb.x + b.y * wb.y + b.z * wb.z + b.w * wb.w;
  }
  cp = wave_reduce(cp);
  const float c_n = cp + be[0];

  // W_energy[512:1536] fragments: 16 floats per lane
  const float4 w0 = *(const float4*)(We + HH + 0 * 256 + lane * 4);
  const float4 w1 = *(const float4*)(We + HH + 1 * 256 + lane * 4);
  const float4 w2 = *(const float4*)(We + HH + 2 * 256 + lane * 4);
  const float4 w3 = *(const float4*)(We + HH + 3 * 256 + lane * 4);

  float4 acc0 = {0, 0, 0, 0}, acc1 = {0, 0, 0, 0}, acc2 = {0, 0, 0, 0}, acc3 = {0, 0, 0, 0};
  float sumw = 0.f;

  const int sBase = chunk * 64 + wave * 16;
#pragma unroll 2
  for (int i = 0; i < 16; ++i) {
    const float* row = enc + ((size_t)(sBase + i) * NN_ + n) * TWO_H;
    float4 e0 = *(const float4*)(row + 0 * 256 + lane * 4);
    float4 e1 = *(const float4*)(row + 1 * 256 + lane * 4);
    float4 e2 = *(const float4*)(row + 2 * 256 + lane * 4);
    float4 e3 = *(const float4*)(row + 3 * 256 + lane * 4);
    float d = e0.x * w0.x + e0.y * w0.y + e0.z * w0.z + e0.w * w0.w +
              e1.x * w1.x + e1.y * w1.y + e1.z * w1.z + e1.w * w1.w +
              e2.x * w2.x + e2.y * w2.y + e2.z * w2.z + e2.w * w2.w +
              e3.x * w3.x + e3.y * w3.y + e3.z * w3.z + e3.w * w3.w;
    d = wave_reduce(d);
    float en = c_n + d;
    en = en > 0.f ? en : 0.f;            // relu
    float p = __expf(en - 4.0f);         // softmax shift-invariant; overflow-safe (e <= ~10)
    sumw += p;
    acc0.x = fmaf(p, e0.x, acc0.x); acc0.y = fmaf(p, e0.y, acc0.y);
    acc0.z = fmaf(p, e0.z, acc0.z); acc0.w = fmaf(p, e0.w, acc0.w);
    acc1.x = fmaf(p, e1.x, acc1.x); acc1.y = fmaf(p, e1.y, acc1.y);
    acc1.z = fmaf(p, e1.z, acc1.z); acc1.w = fmaf(p, e1.w, acc1.w);
    acc2.x = fmaf(p, e2.x, acc2.x); acc2.y = fmaf(p, e2.y, acc2.y);
    acc2.z = fmaf(p, e2.z, acc2.z); acc2.w = fmaf(p, e2.w, acc2.w);
    acc3.x = fmaf(p, e3.x, acc3.x); acc3.y = fmaf(p, e3.y, acc3.y);
    acc3.z = fmaf(p, e3.z, acc3.z); acc3.w = fmaf(p, e3.w, acc3.w);
  }

  // deterministic 4-wave combine via per-wave LDS slices (no atomics)
  __shared__ __align__(16) float lacc[4][1024];
  __shared__ float lsum[4];
  *(float4*)&lacc[wave][0 * 256 + lane * 4] = acc0;
  *(float4*)&lacc[wave][1 * 256 + lane * 4] = acc1;
  *(float4*)&lacc[wave][2 * 256 + lane * 4] = acc2;
  *(float4*)&lacc[wave][3 * 256 + lane * 4] = acc3;
  if (lane == 0) lsum[wave] = sumw;  // p uniform across lanes after butterfly
  __syncthreads();

  const int j = t * 4;
  float4 o;
  o.x = lacc[0][j + 0] + lacc[1][j + 0] + lacc[2][j + 0] + lacc[3][j + 0];
  o.y = lacc[0][j + 1] + lacc[1][j + 1] + lacc[2][j + 1] + lacc[3][j + 1];
  o.z = lacc[0][j + 2] + lacc[1][j + 2] + lacc[2][j + 2] + lacc[3][j + 2];
  o.w = lacc[0][j + 3] + lacc[1][j + 3] + lacc[2][j + 3] + lacc[3][j + 3];
  *(float4*)&ws[WS_ACC + (size_t)blk * 1024 + j] = o;
  if (t == 0) ws[WS_SUMW + blk] = lsum[0] + lsum[1] + lsum[2] + lsum[3];
}

// ---------------- K3: reduce partials -> context; build xcat0^T [1792][32] ----------------
__global__ __launch_bounds__(256) void reduce_ctx(
    const int* __restrict__ x, const float* __restrict__ emb,
    const float* __restrict__ hidden, float* ws) {
  const int n = blockIdx.x;
  const int t = threadIdx.x;
  float sumw = 0.f;
#pragma unroll
  for (int c = 0; c < 32; ++c) sumw += ws[WS_SUMW + n * 32 + c];
  const float inv = 1.0f / sumw;
  float4 v = {0, 0, 0, 0};
#pragma unroll 4
  for (int c = 0; c < 32; ++c) {
    float4 a = *(const float4*)&ws[WS_ACC + (size_t)(n * 32 + c) * 1024 + t * 4];
    v.x += a.x; v.y += a.y; v.z += a.z; v.w += a.w;
  }
  const int j = t * 4;
  ws[WS_XCAT0 + (j + 0) * NN_ + n] = v.x * inv;
  ws[WS_XCAT0 + (j + 1) * NN_ + n] = v.y * inv;
  ws[WS_XCAT0 + (j + 2) * NN_ + n] = v.z * inv;
  ws[WS_XCAT0 + (j + 3) * NN_ + n] = v.w * inv;
  if (t < 64) {
    const int e0 = t * 4;
    const int xi = x[n];
#pragma unroll
    for (int q = 0; q < 4; ++q)
      ws[WS_XCAT0 + (1024 + e0 + q) * NN_ + n] = emb[xi * EE + e0 + q];
  }
  if (t < 128) {
    const int k0 = t * 4;
#pragma unroll
    for (int q = 0; q < 4; ++q)
      ws[WS_XCAT0 + (1280 + k0 + q) * NN_ + n] = hidden[(size_t)n * HH + k0 + q];
  }
}

// ---------------- K4: LSTM0 gates, split-K for occupancy ----------------
__global__ __launch_bounds__(256) void gates0_kernel(
    const float* __restrict__ wih0, const float* __restrict__ whh0,
    const float* __restrict__ bih0, const float* __restrict__ bhh0, float* ws) {
  const int b = blockIdx.x;  // 0..511
  const int t = threadIdx.x;
  const int nn = t & 31;
  const int rl = t >> 5;
  if (b < 256) {
    const int r = b * 8 + rl;
    const float* w = wih0 + (size_t)r * 1280;
    float acc = 0.f;
#pragma unroll 8
    for (int k = 0; k < 896; ++k) acc += w[k] * ws[WS_XCAT0 + k * 32 + nn];
    ws[WS_GA0 + r * 32 + nn] = acc;
  } else {
    const int r = (b - 256) * 8 + rl;
    const float* w = wih0 + (size_t)r * 1280;
    float acc = bih0[r] + bhh0[r];
#pragma unroll 8
    for (int k = 896; k < 1280; ++k) acc += w[k] * ws[WS_XCAT0 + k * 32 + nn];
    const float* w2p = whh0 + (size_t)r * 512;
#pragma unroll 8
    for (int k = 0; k < 512; ++k) acc += w2p[k] * ws[WS_XCAT0 + (1280 + k) * 32 + nn];
    ws[WS_GB0 + r * 32 + nn] = acc;
  }
}

// ---------------- K5: LSTM0 elementwise; writes h0/c0 to d_out and xcat1^T ----------------
__global__ __launch_bounds__(256) void lstm0_kernel(
    const float* __restrict__ cell, const float* __restrict__ hidden,
    float* __restrict__ out, float* ws) {
  const int g = blockIdx.x * 256 + threadIdx.x;  // 0..16383
  const int nn = g & 31;
  const int h = g >> 5;
  const float gi = ws[WS_GA0 + (0 + h) * 32 + nn] + ws[WS_GB0 + (0 + h) * 32 + nn];
  const float gf = ws[WS_GA0 + (512 + h) * 32 + nn] + ws[WS_GB0 + (512 + h) * 32 + nn];
  const float gg = ws[WS_GA0 + (1024 + h) * 32 + nn] + ws[WS_GB0 + (1024 + h) * 32 + nn];
  const float go = ws[WS_GA0 + (1536 + h) * 32 + nn] + ws[WS_GB0 + (1536 + h) * 32 + nn];
  const float cprev = cell[(size_t)nn * HH + h];  // cell[0]
  const float c0 = sigmoidf_(gf) * cprev + sigmoidf_(gi) * tanhf(gg);
  const float h0 = sigmoidf_(go) * tanhf(c0);
  out[OUT_H0 + nn * HH + h] = h0;
  out[OUT_C0 + nn * HH + h] = c0;
  ws[WS_XCAT1 + h * 32 + nn] = h0;
  ws[WS_XCAT1 + (512 + h) * 32 + nn] = hidden[(size_t)(NN_ + nn) * HH + h];  // hidden[1]^T
}

// ---------------- K6: LSTM1 gates (natural split: wih1 | whh1) ----------------
__global__ __launch_bounds__(256) void gates1_kernel(
    const float* __restrict__ wih1, const float* __restrict__ whh1,
    const float* __restrict__ bih1, const float* __restrict__ bhh1, float* ws) {
  const int b = blockIdx.x;  // 0..511
  const int t = threadIdx.x;
  const int nn = t & 31;
  const int rl = t >> 5;
  if (b < 256) {
    const int r = b * 8 + rl;
    const float* w = wih1 + (size_t)r * 512;
    float acc = 0.f;
#pragma unroll 8
    for (int k = 0; k < 512; ++k) acc += w[k] * ws[WS_XCAT1 + k * 32 + nn];
    ws[WS_GA1 + r * 32 + nn] = acc;
  } else {
    const int r = (b - 256) * 8 + rl;
    const float* w = whh1 + (size_t)r * 512;
    float acc = bih1[r] + bhh1[r];
#pragma unroll 8
    for (int k = 0; k < 512; ++k) acc += w[k] * ws[WS_XCAT1 + (512 + k) * 32 + nn];
    ws[WS_GB1 + r * 32 + nn] = acc;
  }
}

// ---------------- K7: LSTM1 elementwise; writes h1/c1 to d_out ----------------
__global__ __launch_bounds__(256) void lstm1_kernel(
    const float* __restrict__ cell, float* __restrict__ out, float* ws) {
  const int g = blockIdx.x * 256 + threadIdx.x;
  const int nn = g & 31;
  const int h = g >> 5;
  const float gi = ws[WS_GA1 + (0 + h) * 32 + nn] + ws[WS_GB1 + (0 + h) * 32 + nn];
  const float gf = ws[WS_GA1 + (512 + h) * 32 + nn] + ws[WS_GB1 + (512 + h) * 32 + nn];
  const float gg = ws[WS_GA1 + (1024 + h) * 32 + nn] + ws[WS_GB1 + (1024 + h) * 32 + nn];
  const float go = ws[WS_GA1 + (1536 + h) * 32 + nn] + ws[WS_GB1 + (1536 + h) * 32 + nn];
  const float cprev = cell[(size_t)(NN_ + nn) * HH + h];  // cell[1]
  const float c1 = sigmoidf_(gf) * cprev + sigmoidf_(gi) * tanhf(gg);
  const float h1 = sigmoidf_(go) * tanhf(c1);
  out[OUT_H1 + nn * HH + h] = h1;
  out[OUT_C1 + nn * HH + h] = c1;
}

// ---------------- K8: predictions = h1 @ Wc^T + bc; one wave per output ----------------
__global__ __launch_bounds__(256) void pred_kernel(
    const float* __restrict__ Wc, const float* __restrict__ bc, float* out) {
  const int wid = blockIdx.x * 4 + (threadIdx.x >> 6);  // 0..319
  const int lane = threadIdx.x & 63;
  const int nn = wid / 10;
  const int c = wid % 10;
  const float* hp = out + OUT_H1 + (size_t)nn * HH;
  const float* wp = Wc + (size_t)c * HH;
  float p = 0.f;
#pragma unroll
  for (int j = 0; j < 8; ++j) p += hp[lane * 8 + j] * wp[lane * 8 + j];
  p = wave_reduce(p);
  if (lane == 0) out[OUT_PRED + nn * 10 + c] = p + bc[c];
}

extern "C" void kernel_launch(void* const* d_in, const int* in_sizes, int n_in,
                              void* d_out, int out_size, void* d_ws, size_t ws_size,
                              hipStream_t stream) {
  const int* x = (const int*)d_in[0];
  const float* enc = (const float*)d_in[1];
  const float* hidden = (const float*)d_in[2];
  const float* cell = (const float*)d_in[3];
  const float* We = (const float*)d_in[4];
  const float* be = (const float*)d_in[5];
  const float* emb = (const float*)d_in[6];
  const float* wih0 = (const float*)d_in[7];
  const float* whh0 = (const float*)d_in[8];
  const float* bih0 = (const float*)d_in[9];
  const float* bhh0 = (const float*)d_in[10];
  const float* wih1 = (const float*)d_in[11];
  const float* whh1 = (const float*)d_in[12];
  const float* bih1 = (const float*)d_in[13];
  const float* bhh1 = (const float*)d_in[14];
  const float* Wc = (const float*)d_in[15];
  const float* bc = (const float*)d_in[16];
  float* out = (float*)d_out;
  float* ws = (float*)d_ws;

  hipLaunchKernelGGL(attn_pass, dim3(1024), dim3(256), 0, stream, enc, hidden, We, be, ws);
  hipLaunchKernelGGL(reduce_ctx, dim3(32), dim3(256), 0, stream, x, emb, hidden, ws);
  hipLaunchKernelGGL(gates0_kernel, dim3(512), dim3(256), 0, stream, wih0, whh0, bih0, bhh0, ws);
  hipLaunchKernelGGL(lstm0_kernel, dim3(64), dim3(256), 0, stream, cell, hidden, out, ws);
  hipLaunchKernelGGL(gates1_kernel, dim3(512), dim3(256), 0, stream, wih1, whh1, bih1, bhh1, ws);
  hipLaunchKernelGGL(lstm1_kernel, dim3(64), dim3(256), 0, stream, cell, out, ws);
  hipLaunchKernelGGL(pred_kernel, dim3(80), dim3(256), 0, stream, Wc, bc, out);
}

// Round 2
// 98.121 us; speedup vs baseline: 1.3231x; 1.3231x over previous
//
#include <hip/hip_runtime.h>

#define SS 2048
#define NN_ 32
#define HH 512
#define EE 256
#define TWO_H 1024

// d_out offsets (floats): predictions[32,10], hidden_new[2,32,512], cell_new[2,32,512]
#define OUT_PRED 0
#define OUT_H0 320
#define OUT_H1 16704
#define OUT_C0 33088
#define OUT_C1 49472

// workspace offsets (floats)
#define WS_ACC 0            // [1024 blocks][1024]  (attention partials; dead after reduce_ctx)
#define WS_SUMW 1048576     // [1024]
#define WS_XCAT0 1049600    // [1792][32]: rows 0..1023 ctx, 1024..1279 emb, 1280..1791 hidden[0]^T
// regions below reuse WS_ACC space
#define WS_PG0 0            // [4 chunks][2048 rows][32]
#define WS_XCAT1 262144     // [1024][32]: rows 0..511 h0^T, 512..1023 hidden[1]^T
#define WS_PG1 294912       // [4 chunks][2048 rows][32]

__device__ __forceinline__ float wave_reduce(float v) {
  v += __shfl_xor(v, 32);
  v += __shfl_xor(v, 16);
  v += __shfl_xor(v, 8);
  v += __shfl_xor(v, 4);
  v += __shfl_xor(v, 2);
  v += __shfl_xor(v, 1);
  return v;
}

__device__ __forceinline__ float sigmoidf_(float x) { return 1.0f / (1.0f + __expf(-x)); }

// ---------------- K1: fused energy + online softmax-weighted context accumulation ----------------
__global__ __launch_bounds__(256, 4) void attn_pass(
    const float* __restrict__ enc, const float* __restrict__ hidden,
    const float* __restrict__ We, const float* __restrict__ be,
    float* __restrict__ ws) {
  const int blk = blockIdx.x;
  const int n = blk >> 5;
  const int chunk = blk & 31;
  const int t = threadIdx.x;
  const int wave = t >> 6;
  const int lane = t & 63;

  const float* hl = hidden + (size_t)(NN_ + n) * HH;
  float cp;
  {
    float4 a = *(const float4*)(hl + lane * 8);
    float4 b = *(const float4*)(hl + lane * 8 + 4);
    float4 wa = *(const float4*)(We + lane * 8);
    float4 wb = *(const float4*)(We + lane * 8 + 4);
    cp = a.x * wa.x + a.y * wa.y + a.z * wa.z + a.w * wa.w +
         b.x * wb.x + b.y * wb.y + b.z * wb.z + b.w * wb.w;
  }
  cp = wave_reduce(cp);
  const float c_n = cp + be[0];

  const float4 w0 = *(const float4*)(We + HH + 0 * 256 + lane * 4);
  const float4 w1 = *(const float4*)(We + HH + 1 * 256 + lane * 4);
  const float4 w2 = *(const float4*)(We + HH + 2 * 256 + lane * 4);
  const float4 w3 = *(const float4*)(We + HH + 3 * 256 + lane * 4);

  float4 acc0 = {0, 0, 0, 0}, acc1 = {0, 0, 0, 0}, acc2 = {0, 0, 0, 0}, acc3 = {0, 0, 0, 0};
  float sumw = 0.f;

  const int sBase = chunk * 64 + wave * 16;
#pragma unroll 2
  for (int i = 0; i < 16; ++i) {
    const float* row = enc + ((size_t)(sBase + i) * NN_ + n) * TWO_H;
    float4 e0 = *(const float4*)(row + 0 * 256 + lane * 4);
    float4 e1 = *(const float4*)(row + 1 * 256 + lane * 4);
    float4 e2 = *(const float4*)(row + 2 * 256 + lane * 4);
    float4 e3 = *(const float4*)(row + 3 * 256 + lane * 4);
    float d = e0.x * w0.x + e0.y * w0.y + e0.z * w0.z + e0.w * w0.w +
              e1.x * w1.x + e1.y * w1.y + e1.z * w1.z + e1.w * w1.w +
              e2.x * w2.x + e2.y * w2.y + e2.z * w2.z + e2.w * w2.w +
              e3.x * w3.x + e3.y * w3.y + e3.z * w3.z + e3.w * w3.w;
    d = wave_reduce(d);
    float en = c_n + d;
    en = en > 0.f ? en : 0.f;
    float p = __expf(en - 4.0f);
    sumw += p;
    acc0.x = fmaf(p, e0.x, acc0.x); acc0.y = fmaf(p, e0.y, acc0.y);
    acc0.z = fmaf(p, e0.z, acc0.z); acc0.w = fmaf(p, e0.w, acc0.w);
    acc1.x = fmaf(p, e1.x, acc1.x); acc1.y = fmaf(p, e1.y, acc1.y);
    acc1.z = fmaf(p, e1.z, acc1.z); acc1.w = fmaf(p, e1.w, acc1.w);
    acc2.x = fmaf(p, e2.x, acc2.x); acc2.y = fmaf(p, e2.y, acc2.y);
    acc2.z = fmaf(p, e2.z, acc2.z); acc2.w = fmaf(p, e2.w, acc2.w);
    acc3.x = fmaf(p, e3.x, acc3.x); acc3.y = fmaf(p, e3.y, acc3.y);
    acc3.z = fmaf(p, e3.z, acc3.z); acc3.w = fmaf(p, e3.w, acc3.w);
  }

  __shared__ __align__(16) float lacc[4][1024];
  __shared__ float lsum[4];
  *(float4*)&lacc[wave][0 * 256 + lane * 4] = acc0;
  *(float4*)&lacc[wave][1 * 256 + lane * 4] = acc1;
  *(float4*)&lacc[wave][2 * 256 + lane * 4] = acc2;
  *(float4*)&lacc[wave][3 * 256 + lane * 4] = acc3;
  if (lane == 0) lsum[wave] = sumw;
  __syncthreads();

  const int j = t * 4;
  float4 o;
  o.x = lacc[0][j + 0] + lacc[1][j + 0] + lacc[2][j + 0] + lacc[3][j + 0];
  o.y = lacc[0][j + 1] + lacc[1][j + 1] + lacc[2][j + 1] + lacc[3][j + 1];
  o.z = lacc[0][j + 2] + lacc[1][j + 2] + lacc[2][j + 2] + lacc[3][j + 2];
  o.w = lacc[0][j + 3] + lacc[1][j + 3] + lacc[2][j + 3] + lacc[3][j + 3];
  *(float4*)&ws[WS_ACC + (size_t)blk * 1024 + j] = o;
  if (t == 0) ws[WS_SUMW + blk] = lsum[0] + lsum[1] + lsum[2] + lsum[3];
}

// ---------------- K2: reduce partials -> context; build xcat0 [k][32] ----------------
__global__ __launch_bounds__(256) void reduce_ctx(
    const int* __restrict__ x, const float* __restrict__ emb,
    const float* __restrict__ hidden, float* ws) {
  const int n = blockIdx.x;
  const int t = threadIdx.x;
  float sumw = 0.f;
#pragma unroll
  for (int c = 0; c < 32; ++c) sumw += ws[WS_SUMW + n * 32 + c];
  const float inv = 1.0f / sumw;
  float4 v = {0, 0, 0, 0};
#pragma unroll 4
  for (int c = 0; c < 32; ++c) {
    float4 a = *(const float4*)&ws[WS_ACC + (size_t)(n * 32 + c) * 1024 + t * 4];
    v.x += a.x; v.y += a.y; v.z += a.z; v.w += a.w;
  }
  const int j = t * 4;
  ws[WS_XCAT0 + (j + 0) * NN_ + n] = v.x * inv;
  ws[WS_XCAT0 + (j + 1) * NN_ + n] = v.y * inv;
  ws[WS_XCAT0 + (j + 2) * NN_ + n] = v.z * inv;
  ws[WS_XCAT0 + (j + 3) * NN_ + n] = v.w * inv;
  if (t < 64) {
    const int e0 = t * 4;
    const int xi = x[n];
#pragma unroll
    for (int q = 0; q < 4; ++q)
      ws[WS_XCAT0 + (1024 + e0 + q) * NN_ + n] = emb[xi * EE + e0 + q];
  }
  if (t < 128) {
    const int k0 = t * 4;
#pragma unroll
    for (int q = 0; q < 4; ++q)
      ws[WS_XCAT0 + (1280 + k0 + q) * NN_ + n] = hidden[(size_t)n * HH + k0 + q];
  }
}

// ---------------- K3: LSTM0 gates, 4-way K-split, all 4 gates per thread, LDS-staged x --------
// 256 blocks: chunk = bid&3 over K-ranges {[0,448),[448,896),[896,1344),[1344,1792)}, hg = bid>>2.
__global__ __launch_bounds__(256) void gates0_kernel(
    const float* __restrict__ wih0, const float* __restrict__ whh0, float* __restrict__ ws) {
  __shared__ __align__(16) float xs[448 * 32];  // 56 KB
  const int bid = blockIdx.x;
  const int chunk = bid & 3;
  const int hg = bid >> 2;
  const int t = threadIdx.x;
  const int nn = t & 31;
  const int rl = t >> 5;
  const int h = hg * 8 + rl;

  const int kb = chunk * 448;
  const int ke = kb + 448;

  const float* src = ws + WS_XCAT0 + (size_t)kb * 32;
  for (int i = t * 4; i < 448 * 32; i += 1024)
    *(float4*)&xs[i] = *(const float4*)&src[i];
  __syncthreads();

  float a0 = 0.f, a1 = 0.f, a2 = 0.f, a3 = 0.f;

  // segment 0: k in [kb, min(ke,1280)) -> wih0 columns
  {
    const int s0e = ke < 1280 ? ke : 1280;
    if (kb < s0e) {
      const float* p0 = wih0 + (size_t)(0 * 512 + h) * 1280 + kb;
      const float* p1 = wih0 + (size_t)(1 * 512 + h) * 1280 + kb;
      const float* p2 = wih0 + (size_t)(2 * 512 + h) * 1280 + kb;
      const float* p3 = wih0 + (size_t)(3 * 512 + h) * 1280 + kb;
      const int len = s0e - kb;
#pragma unroll 2
      for (int k = 0; k < len; k += 4) {
        const float4 w0 = *(const float4*)(p0 + k);
        const float4 w1 = *(const float4*)(p1 + k);
        const float4 w2 = *(const float4*)(p2 + k);
        const float4 w3 = *(const float4*)(p3 + k);
        const float x0 = xs[(k + 0) * 32 + nn];
        const float x1 = xs[(k + 1) * 32 + nn];
        const float x2 = xs[(k + 2) * 32 + nn];
        const float x3 = xs[(k + 3) * 32 + nn];
        a0 += w0.x * x0 + w0.y * x1 + w0.z * x2 + w0.w * x3;
        a1 += w1.x * x0 + w1.y * x1 + w1.z * x2 + w1.w * x3;
        a2 += w2.x * x0 + w2.y * x1 + w2.z * x2 + w2.w * x3;
        a3 += w3.x * x0 + w3.y * x1 + w3.z * x2 + w3.w * x3;
      }
    }
  }
  // segment 1: k in [max(kb,1280), ke) -> whh0 columns
  {
    const int s1b = kb > 1280 ? kb : 1280;
    if (s1b < ke) {
      const int xoff = s1b - kb;
      const float* q0 = whh0 + (size_t)(0 * 512 + h) * 512 + (s1b - 1280);
      const float* q1 = whh0 + (size_t)(1 * 512 + h) * 512 + (s1b - 1280);
      const float* q2 = whh0 + (size_t)(2 * 512 + h) * 512 + (s1b - 1280);
      const float* q3 = whh0 + (size_t)(3 * 512 + h) * 512 + (s1b - 1280);
      const int len = ke - s1b;
#pragma unroll 2
      for (int k = 0; k < len; k += 4) {
        const float4 w0 = *(const float4*)(q0 + k);
        const float4 w1 = *(const float4*)(q1 + k);
        const float4 w2 = *(const float4*)(q2 + k);
        const float4 w3 = *(const float4*)(q3 + k);
        const float x0 = xs[(k + xoff + 0) * 32 + nn];
        const float x1 = xs[(k + xoff + 1) * 32 + nn];
        const float x2 = xs[(k + xoff + 2) * 32 + nn];
        const float x3 = xs[(k + xoff + 3) * 32 + nn];
        a0 += w0.x * x0 + w0.y * x1 + w0.z * x2 + w0.w * x3;
        a1 += w1.x * x0 + w1.y * x1 + w1.z * x2 + w1.w * x3;
        a2 += w2.x * x0 + w2.y * x1 + w2.z * x2 + w2.w * x3;
        a3 += w3.x * x0 + w3.y * x1 + w3.z * x2 + w3.w * x3;
      }
    }
  }

  float* dst = ws + WS_PG0 + ((size_t)chunk * 2048 + h) * 32 + nn;
  dst[0 * 512 * 32] = a0;
  dst[1 * 512 * 32] = a1;
  dst[2 * 512 * 32] = a2;
  dst[3 * 512 * 32] = a3;
}

// ---------------- K4: LSTM0 combine + elementwise; writes h0/c0 and xcat1 ----------------
__global__ __launch_bounds__(256) void lstm0_kernel(
    const float* __restrict__ cell, const float* __restrict__ hidden,
    const float* __restrict__ bih0, const float* __restrict__ bhh0,
    float* __restrict__ out, float* __restrict__ ws) {
  const int g = blockIdx.x * 256 + threadIdx.x;  // 16384
  const int nn = g & 31;
  const int h = g >> 5;
  float gi = bih0[h] + bhh0[h];
  float gf = bih0[512 + h] + bhh0[512 + h];
  float gg = bih0[1024 + h] + bhh0[1024 + h];
  float go = bih0[1536 + h] + bhh0[1536 + h];
#pragma unroll
  for (int c = 0; c < 4; ++c) {
    const float* p = ws + WS_PG0 + (size_t)c * 2048 * 32;
    gi += p[(0 * 512 + h) * 32 + nn];
    gf += p[(1 * 512 + h) * 32 + nn];
    gg += p[(2 * 512 + h) * 32 + nn];
    go += p[(3 * 512 + h) * 32 + nn];
  }
  const float cprev = cell[(size_t)nn * HH + h];
  const float c0 = sigmoidf_(gf) * cprev + sigmoidf_(gi) * tanhf(gg);
  const float h0 = sigmoidf_(go) * tanhf(c0);
  out[OUT_H0 + nn * HH + h] = h0;
  out[OUT_C0 + nn * HH + h] = c0;
  ws[WS_XCAT1 + h * 32 + nn] = h0;
  ws[WS_XCAT1 + (512 + h) * 32 + nn] = hidden[(size_t)(NN_ + nn) * HH + h];
}

// ---------------- K5: LSTM1 gates, 4-way K-split ----------------
__global__ __launch_bounds__(256) void gates1_kernel(
    const float* __restrict__ wih1, const float* __restrict__ whh1, float* __restrict__ ws) {
  __shared__ __align__(16) float xs[256 * 32];  // 32 KB
  const int bid = blockIdx.x;
  const int chunk = bid & 3;
  const int hg = bid >> 2;
  const int t = threadIdx.x;
  const int nn = t & 31;
  const int rl = t >> 5;
  const int h = hg * 8 + rl;
  const int kb = chunk * 256;

  const float* src = ws + WS_XCAT1 + (size_t)kb * 32;
  for (int i = t * 4; i < 256 * 32; i += 1024)
    *(float4*)&xs[i] = *(const float4*)&src[i];
  __syncthreads();

  const float* base = (chunk < 2) ? wih1 : whh1;
  const int koff = (chunk < 2) ? kb : kb - 512;
  const float* p0 = base + (size_t)(0 * 512 + h) * 512 + koff;
  const float* p1 = base + (size_t)(1 * 512 + h) * 512 + koff;
  const float* p2 = base + (size_t)(2 * 512 + h) * 512 + koff;
  const float* p3 = base + (size_t)(3 * 512 + h) * 512 + koff;

  float a0 = 0.f, a1 = 0.f, a2 = 0.f, a3 = 0.f;
#pragma unroll 2
  for (int k = 0; k < 256; k += 4) {
    const float4 w0 = *(const float4*)(p0 + k);
    const float4 w1 = *(const float4*)(p1 + k);
    const float4 w2 = *(const float4*)(p2 + k);
    const float4 w3 = *(const float4*)(p3 + k);
    const float x0 = xs[(k + 0) * 32 + nn];
    const float x1 = xs[(k + 1) * 32 + nn];
    const float x2 = xs[(k + 2) * 32 + nn];
    const float x3 = xs[(k + 3) * 32 + nn];
    a0 += w0.x * x0 + w0.y * x1 + w0.z * x2 + w0.w * x3;
    a1 += w1.x * x0 + w1.y * x1 + w1.z * x2 + w1.w * x3;
    a2 += w2.x * x0 + w2.y * x1 + w2.z * x2 + w2.w * x3;
    a3 += w3.x * x0 + w3.y * x1 + w3.z * x2 + w3.w * x3;
  }

  float* dst = ws + WS_PG1 + ((size_t)chunk * 2048 + h) * 32 + nn;
  dst[0 * 512 * 32] = a0;
  dst[1 * 512 * 32] = a1;
  dst[2 * 512 * 32] = a2;
  dst[3 * 512 * 32] = a3;
}

// ---------------- K6: LSTM1 combine + elementwise; writes h1/c1 ----------------
__global__ __launch_bounds__(256) void lstm1_kernel(
    const float* __restrict__ cell,
    const float* __restrict__ bih1, const float* __restrict__ bhh1,
    float* __restrict__ out, float* __restrict__ ws) {
  const int g = blockIdx.x * 256 + threadIdx.x;
  const int nn = g & 31;
  const int h = g >> 5;
  float gi = bih1[h] + bhh1[h];
  float gf = bih1[512 + h] + bhh1[512 + h];
  float gg = bih1[1024 + h] + bhh1[1024 + h];
  float go = bih1[1536 + h] + bhh1[1536 + h];
#pragma unroll
  for (int c = 0; c < 4; ++c) {
    const float* p = ws + WS_PG1 + (size_t)c * 2048 * 32;
    gi += p[(0 * 512 + h) * 32 + nn];
    gf += p[(1 * 512 + h) * 32 + nn];
    gg += p[(2 * 512 + h) * 32 + nn];
    go += p[(3 * 512 + h) * 32 + nn];
  }
  const float cprev = cell[(size_t)(NN_ + nn) * HH + h];
  const float c1 = sigmoidf_(gf) * cprev + sigmoidf_(gi) * tanhf(gg);
  const float h1 = sigmoidf_(go) * tanhf(c1);
  out[OUT_H1 + nn * HH + h] = h1;
  out[OUT_C1 + nn * HH + h] = c1;
}

// ---------------- K7: predictions ----------------
__global__ __launch_bounds__(256) void pred_kernel(
    const float* __restrict__ Wc, const float* __restrict__ bc, float* out) {
  const int wid = blockIdx.x * 4 + (threadIdx.x >> 6);  // 0..319
  const int lane = threadIdx.x & 63;
  const int nn = wid / 10;
  const int c = wid % 10;
  const float* hp = out + OUT_H1 + (size_t)nn * HH;
  const float* wp = Wc + (size_t)c * HH;
  float p = 0.f;
#pragma unroll
  for (int j = 0; j < 8; ++j) p += hp[lane * 8 + j] * wp[lane * 8 + j];
  p = wave_reduce(p);
  if (lane == 0) out[OUT_PRED + nn * 10 + c] = p + bc[c];
}

extern "C" void kernel_launch(void* const* d_in, const int* in_sizes, int n_in,
                              void* d_out, int out_size, void* d_ws, size_t ws_size,
                              hipStream_t stream) {
  const int* x = (const int*)d_in[0];
  const float* enc = (const float*)d_in[1];
  const float* hidden = (const float*)d_in[2];
  const float* cell = (const float*)d_in[3];
  const float* We = (const float*)d_in[4];
  const float* be = (const float*)d_in[5];
  const float* emb = (const float*)d_in[6];
  const float* wih0 = (const float*)d_in[7];
  const float* whh0 = (const float*)d_in[8];
  const float* bih0 = (const float*)d_in[9];
  const float* bhh0 = (const float*)d_in[10];
  const float* wih1 = (const float*)d_in[11];
  const float* whh1 = (const float*)d_in[12];
  const float* bih1 = (const float*)d_in[13];
  const float* bhh1 = (const float*)d_in[14];
  const float* Wc = (const float*)d_in[15];
  const float* bc = (const float*)d_in[16];
  float* out = (float*)d_out;
  float* ws = (float*)d_ws;

  hipLaunchKernelGGL(attn_pass, dim3(1024), dim3(256), 0, stream, enc, hidden, We, be, ws);
  hipLaunchKernelGGL(reduce_ctx, dim3(32), dim3(256), 0, stream, x, emb, hidden, ws);
  hipLaunchKernelGGL(gates0_kernel, dim3(256), dim3(256), 0, stream, wih0, whh0, ws);
  hipLaunchKernelGGL(lstm0_kernel, dim3(64), dim3(256), 0, stream, cell, hidden, bih0, bhh0, out, ws);
  hipLaunchKernelGGL(gates1_kernel, dim3(256), dim3(256), 0, stream, wih1, whh1, ws);
  hipLaunchKernelGGL(lstm1_kernel, dim3(64), dim3(256), 0, stream, cell, bih1, bhh1, out, ws);
  hipLaunchKernelGGL(pred_kernel, dim3(80), dim3(256), 0, stream, Wc, bc, out);
}

// Round 3
// 78.942 us; speedup vs baseline: 1.6446x; 1.2430x over previous
//
#include <hip/hip_runtime.h>

#define SS 2048
#define NN_ 32
#define HH 512
#define EE 256
#define TWO_H 1024

// d_out offsets (floats): predictions[32,10], hidden_new[2,32,512], cell_new[2,32,512]
#define OUT_PRED 0
#define OUT_H0 320
#define OUT_H1 16704
#define OUT_C0 33088
#define OUT_C1 49472

// workspace offsets (floats)
#define WS_ACC 0            // [1024 blocks][1024]  attention partials (dead after reduce_ctx)
#define WS_SUMW 1048576     // [1024]
#define WS_XCAT0 1049600    // [1792][32]: rows 0..1023 ctx, 1024..1279 emb, 1280..1791 hidden[0]^T
// tail regions reuse WS_ACC space (attention partials dead)
#define WS_PG0 0            // [7 chunks][2048 rows][32] = 458752
#define WS_XCAT1 458752     // [1024][32]: rows 0..511 h0^T, 512..1023 hidden[1]^T
#define WS_PG1 491520       // [8 chunks][2048 rows][32] = 524288 (ends 1015808 < 1048576)

__device__ __forceinline__ float wave_reduce(float v) {
  v += __shfl_xor(v, 32);
  v += __shfl_xor(v, 16);
  v += __shfl_xor(v, 8);
  v += __shfl_xor(v, 4);
  v += __shfl_xor(v, 2);
  v += __shfl_xor(v, 1);
  return v;
}

__device__ __forceinline__ float sigmoidf_(float x) { return 1.0f / (1.0f + __expf(-x)); }

// ---------------- K1: fused energy + online softmax-weighted context accumulation ----------------
__global__ __launch_bounds__(256, 4) void attn_pass(
    const float* __restrict__ enc, const float* __restrict__ hidden,
    const float* __restrict__ We, const float* __restrict__ be,
    float* __restrict__ ws) {
  const int blk = blockIdx.x;
  const int n = blk >> 5;
  const int chunk = blk & 31;
  const int t = threadIdx.x;
  const int wave = t >> 6;
  const int lane = t & 63;

  const float* hl = hidden + (size_t)(NN_ + n) * HH;
  float cp;
  {
    float4 a = *(const float4*)(hl + lane * 8);
    float4 b = *(const float4*)(hl + lane * 8 + 4);
    float4 wa = *(const float4*)(We + lane * 8);
    float4 wb = *(const float4*)(We + lane * 8 + 4);
    cp = a.x * wa.x + a.y * wa.y + a.z * wa.z + a.w * wa.w +
         b.x * wb.x + b.y * wb.y + b.z * wb.z + b.w * wb.w;
  }
  cp = wave_reduce(cp);
  const float c_n = cp + be[0];

  const float4 w0 = *(const float4*)(We + HH + 0 * 256 + lane * 4);
  const float4 w1 = *(const float4*)(We + HH + 1 * 256 + lane * 4);
  const float4 w2 = *(const float4*)(We + HH + 2 * 256 + lane * 4);
  const float4 w3 = *(const float4*)(We + HH + 3 * 256 + lane * 4);

  float4 acc0 = {0, 0, 0, 0}, acc1 = {0, 0, 0, 0}, acc2 = {0, 0, 0, 0}, acc3 = {0, 0, 0, 0};
  float sumw = 0.f;

  const int sBase = chunk * 64 + wave * 16;
#pragma unroll 2
  for (int i = 0; i < 16; ++i) {
    const float* row = enc + ((size_t)(sBase + i) * NN_ + n) * TWO_H;
    float4 e0 = *(const float4*)(row + 0 * 256 + lane * 4);
    float4 e1 = *(const float4*)(row + 1 * 256 + lane * 4);
    float4 e2 = *(const float4*)(row + 2 * 256 + lane * 4);
    float4 e3 = *(const float4*)(row + 3 * 256 + lane * 4);
    float d = e0.x * w0.x + e0.y * w0.y + e0.z * w0.z + e0.w * w0.w +
              e1.x * w1.x + e1.y * w1.y + e1.z * w1.z + e1.w * w1.w +
              e2.x * w2.x + e2.y * w2.y + e2.z * w2.z + e2.w * w2.w +
              e3.x * w3.x + e3.y * w3.y + e3.z * w3.z + e3.w * w3.w;
    d = wave_reduce(d);
    float en = c_n + d;
    en = en > 0.f ? en : 0.f;
    float p = __expf(en - 4.0f);
    sumw += p;
    acc0.x = fmaf(p, e0.x, acc0.x); acc0.y = fmaf(p, e0.y, acc0.y);
    acc0.z = fmaf(p, e0.z, acc0.z); acc0.w = fmaf(p, e0.w, acc0.w);
    acc1.x = fmaf(p, e1.x, acc1.x); acc1.y = fmaf(p, e1.y, acc1.y);
    acc1.z = fmaf(p, e1.z, acc1.z); acc1.w = fmaf(p, e1.w, acc1.w);
    acc2.x = fmaf(p, e2.x, acc2.x); acc2.y = fmaf(p, e2.y, acc2.y);
    acc2.z = fmaf(p, e2.z, acc2.z); acc2.w = fmaf(p, e2.w, acc2.w);
    acc3.x = fmaf(p, e3.x, acc3.x); acc3.y = fmaf(p, e3.y, acc3.y);
    acc3.z = fmaf(p, e3.z, acc3.z); acc3.w = fmaf(p, e3.w, acc3.w);
  }

  __shared__ __align__(16) float lacc[4][1024];
  __shared__ float lsum[4];
  *(float4*)&lacc[wave][0 * 256 + lane * 4] = acc0;
  *(float4*)&lacc[wave][1 * 256 + lane * 4] = acc1;
  *(float4*)&lacc[wave][2 * 256 + lane * 4] = acc2;
  *(float4*)&lacc[wave][3 * 256 + lane * 4] = acc3;
  if (lane == 0) lsum[wave] = sumw;
  __syncthreads();

  const int j = t * 4;
  float4 o;
  o.x = lacc[0][j + 0] + lacc[1][j + 0] + lacc[2][j + 0] + lacc[3][j + 0];
  o.y = lacc[0][j + 1] + lacc[1][j + 1] + lacc[2][j + 1] + lacc[3][j + 1];
  o.z = lacc[0][j + 2] + lacc[1][j + 2] + lacc[2][j + 2] + lacc[3][j + 2];
  o.w = lacc[0][j + 3] + lacc[1][j + 3] + lacc[2][j + 3] + lacc[3][j + 3];
  *(float4*)&ws[WS_ACC + (size_t)blk * 1024 + j] = o;
  if (t == 0) ws[WS_SUMW + blk] = lsum[0] + lsum[1] + lsum[2] + lsum[3];
}

// ---------------- K2: reduce partials -> context; build xcat0 [k][32]; 256 blocks ----------------
__global__ __launch_bounds__(256) void reduce_ctx(
    const int* __restrict__ x, const float* __restrict__ emb,
    const float* __restrict__ hidden, float* __restrict__ ws) {
  const int b = blockIdx.x;
  const int n = b >> 3;
  const int jg = b & 7;
  const int t = threadIdx.x;
  if (t < 128) {
    const int j = jg * 128 + t;
    float sumw = 0.f;
#pragma unroll
    for (int c = 0; c < 32; ++c) sumw += ws[WS_SUMW + n * 32 + c];
    const float inv = 1.0f / sumw;
    float v = 0.f;
#pragma unroll 8
    for (int c = 0; c < 32; ++c) v += ws[WS_ACC + (size_t)(n * 32 + c) * 1024 + j];
    ws[WS_XCAT0 + j * NN_ + n] = v * inv;
  } else if (t < 224) {
    const int row = jg * 96 + (t - 128);  // 0..767: 0..255 emb, 256..767 hidden[0]
    float v;
    if (row < 256) {
      v = emb[(size_t)x[n] * EE + row];
    } else {
      v = hidden[(size_t)n * HH + (row - 256)];
    }
    ws[WS_XCAT0 + (1024 + row) * NN_ + n] = v;
  }
}

// ---------------- K3: LSTM0 gates. 448 blocks = 64 hg x 7 K-chunks (Kc=256).
// chunks 0-4 -> wih0 cols [chunk*256, +256); chunks 5,6 -> whh0 cols [(chunk-5)*256, +256).
// LDS-staged coalesced weight tile [32][260] + xs [256][32]. ----------------
__global__ __launch_bounds__(256, 2) void gates0_kernel(
    const float* __restrict__ wih0, const float* __restrict__ whh0, float* __restrict__ ws) {
  __shared__ __align__(16) float xs[256 * 32];     // 32 KB
  __shared__ __align__(16) float wt[32 * 260];     // 33.3 KB (pad 260 breaks bank aliasing)
  const int bid = blockIdx.x;
  const int chunk = bid % 7;
  const int hg = bid / 7;
  const int t = threadIdx.x;
  const int nn = t & 31;
  const int rl = t >> 5;

  // stage xs: 8192 floats from XCAT0 rows [chunk*256, +256)
  {
    const float* src = ws + WS_XCAT0 + (size_t)chunk * 256 * 32;
#pragma unroll
    for (int i = t * 4; i < 8192; i += 1024)
      *(float4*)&xs[i] = *(const float4*)&src[i];
  }
  // stage weights: 32 rows (4 gates x 8 h) x 256 cols, coalesced (8 lanes x 16B contiguous)
  {
    const int r = t >> 3;        // 0..31: gate = r>>3, hrow = hg*8 + (r&7)
    const int k8 = t & 7;
    const int grow = (r >> 3) * 512 + hg * 8 + (r & 7);
    const float* src = (chunk < 5) ? (wih0 + (size_t)grow * 1280 + chunk * 256)
                                   : (whh0 + (size_t)grow * 512 + (chunk - 5) * 256);
#pragma unroll
    for (int jj = 0; jj < 8; ++jj) {
      const int kl = jj * 32 + k8 * 4;
      *(float4*)&wt[r * 260 + kl] = *(const float4*)(src + kl);
    }
  }
  __syncthreads();

  const float* w0p = &wt[(0 * 8 + rl) * 260];
  const float* w1p = &wt[(1 * 8 + rl) * 260];
  const float* w2p = &wt[(2 * 8 + rl) * 260];
  const float* w3p = &wt[(3 * 8 + rl) * 260];

  float a0 = 0.f, a1 = 0.f, a2 = 0.f, a3 = 0.f;
#pragma unroll 4
  for (int k = 0; k < 256; k += 4) {
    const float4 w0 = *(const float4*)(w0p + k);
    const float4 w1 = *(const float4*)(w1p + k);
    const float4 w2 = *(const float4*)(w2p + k);
    const float4 w3 = *(const float4*)(w3p + k);
    const float x0 = xs[(k + 0) * 32 + nn];
    const float x1 = xs[(k + 1) * 32 + nn];
    const float x2 = xs[(k + 2) * 32 + nn];
    const float x3 = xs[(k + 3) * 32 + nn];
    a0 += w0.x * x0 + w0.y * x1 + w0.z * x2 + w0.w * x3;
    a1 += w1.x * x0 + w1.y * x1 + w1.z * x2 + w1.w * x3;
    a2 += w2.x * x0 + w2.y * x1 + w2.z * x2 + w2.w * x3;
    a3 += w3.x * x0 + w3.y * x1 + w3.z * x2 + w3.w * x3;
  }

  const int h = hg * 8 + rl;
  float* dst = ws + WS_PG0 + ((size_t)chunk * 2048 + h) * 32 + nn;
  dst[0 * 512 * 32] = a0;
  dst[1 * 512 * 32] = a1;
  dst[2 * 512 * 32] = a2;
  dst[3 * 512 * 32] = a3;
}

// ---------------- K4: LSTM0 combine + elementwise; writes h0/c0 and xcat1 ----------------
__global__ __launch_bounds__(256) void lstm0_kernel(
    const float* __restrict__ cell, const float* __restrict__ hidden,
    const float* __restrict__ bih0, const float* __restrict__ bhh0,
    float* __restrict__ out, float* __restrict__ ws) {
  const int g = blockIdx.x * 256 + threadIdx.x;  // 16384
  const int nn = g & 31;
  const int h = g >> 5;
  float gi = bih0[h] + bhh0[h];
  float gf = bih0[512 + h] + bhh0[512 + h];
  float gg = bih0[1024 + h] + bhh0[1024 + h];
  float go = bih0[1536 + h] + bhh0[1536 + h];
#pragma unroll
  for (int c = 0; c < 7; ++c) {
    const float* p = ws + WS_PG0 + (size_t)c * 2048 * 32;
    gi += p[(0 * 512 + h) * 32 + nn];
    gf += p[(1 * 512 + h) * 32 + nn];
    gg += p[(2 * 512 + h) * 32 + nn];
    go += p[(3 * 512 + h) * 32 + nn];
  }
  const float cprev = cell[(size_t)nn * HH + h];
  const float c0 = sigmoidf_(gf) * cprev + sigmoidf_(gi) * tanhf(gg);
  const float h0 = sigmoidf_(go) * tanhf(c0);
  out[OUT_H0 + nn * HH + h] = h0;
  out[OUT_C0 + nn * HH + h] = c0;
  ws[WS_XCAT1 + h * 32 + nn] = h0;
  ws[WS_XCAT1 + (512 + h) * 32 + nn] = hidden[(size_t)(NN_ + nn) * HH + h];
}

// ---------------- K5: LSTM1 gates. 512 blocks = 64 hg x 8 K-chunks (Kc=128).
// chunks 0-3 -> wih1, chunks 4-7 -> whh1. ----------------
__global__ __launch_bounds__(256, 2) void gates1_kernel(
    const float* __restrict__ wih1, const float* __restrict__ whh1, float* __restrict__ ws) {
  __shared__ __align__(16) float xs[128 * 32];     // 16 KB
  __shared__ __align__(16) float wt[32 * 132];     // 16.9 KB
  const int bid = blockIdx.x;
  const int chunk = bid & 7;
  const int hg = bid >> 3;
  const int t = threadIdx.x;
  const int nn = t & 31;
  const int rl = t >> 5;
  const int kb = chunk * 128;

  {
    const float* src = ws + WS_XCAT1 + (size_t)kb * 32;
#pragma unroll
    for (int i = t * 4; i < 4096; i += 1024)
      *(float4*)&xs[i] = *(const float4*)&src[i];
  }
  {
    const int r = t >> 3;
    const int k8 = t & 7;
    const int grow = (r >> 3) * 512 + hg * 8 + (r & 7);
    const float* src = (chunk < 4) ? (wih1 + (size_t)grow * 512 + kb)
                                   : (whh1 + (size_t)grow * 512 + (kb - 512));
#pragma unroll
    for (int jj = 0; jj < 4; ++jj) {
      const int kl = jj * 32 + k8 * 4;
      *(float4*)&wt[r * 132 + kl] = *(const float4*)(src + kl);
    }
  }
  __syncthreads();

  const float* w0p = &wt[(0 * 8 + rl) * 132];
  const float* w1p = &wt[(1 * 8 + rl) * 132];
  const float* w2p = &wt[(2 * 8 + rl) * 132];
  const float* w3p = &wt[(3 * 8 + rl) * 132];

  float a0 = 0.f, a1 = 0.f, a2 = 0.f, a3 = 0.f;
#pragma unroll 4
  for (int k = 0; k < 128; k += 4) {
    const float4 w0 = *(const float4*)(w0p + k);
    const float4 w1 = *(const float4*)(w1p + k);
    const float4 w2 = *(const float4*)(w2p + k);
    const float4 w3 = *(const float4*)(w3p + k);
    const float x0 = xs[(k + 0) * 32 + nn];
    const float x1 = xs[(k + 1) * 32 + nn];
    const float x2 = xs[(k + 2) * 32 + nn];
    const float x3 = xs[(k + 3) * 32 + nn];
    a0 += w0.x * x0 + w0.y * x1 + w0.z * x2 + w0.w * x3;
    a1 += w1.x * x0 + w1.y * x1 + w1.z * x2 + w1.w * x3;
    a2 += w2.x * x0 + w2.y * x1 + w2.z * x2 + w2.w * x3;
    a3 += w3.x * x0 + w3.y * x1 + w3.z * x2 + w3.w * x3;
  }

  const int h = hg * 8 + rl;
  float* dst = ws + WS_PG1 + ((size_t)chunk * 2048 + h) * 32 + nn;
  dst[0 * 512 * 32] = a0;
  dst[1 * 512 * 32] = a1;
  dst[2 * 512 * 32] = a2;
  dst[3 * 512 * 32] = a3;
}

// ---------------- K6: LSTM1 combine + elementwise; writes h1/c1 ----------------
__global__ __launch_bounds__(256) void lstm1_kernel(
    const float* __restrict__ cell,
    const float* __restrict__ bih1, const float* __restrict__ bhh1,
    float* __restrict__ out, float* __restrict__ ws) {
  const int g = blockIdx.x * 256 + threadIdx.x;
  const int nn = g & 31;
  const int h = g >> 5;
  float gi = bih1[h] + bhh1[h];
  float gf = bih1[512 + h] + bhh1[512 + h];
  float gg = bih1[1024 + h] + bhh1[1024 + h];
  float go = bih1[1536 + h] + bhh1[1536 + h];
#pragma unroll
  for (int c = 0; c < 8; ++c) {
    const float* p = ws + WS_PG1 + (size_t)c * 2048 * 32;
    gi += p[(0 * 512 + h) * 32 + nn];
    gf += p[(1 * 512 + h) * 32 + nn];
    gg += p[(2 * 512 + h) * 32 + nn];
    go += p[(3 * 512 + h) * 32 + nn];
  }
  const float cprev = cell[(size_t)(NN_ + nn) * HH + h];
  const float c1 = sigmoidf_(gf) * cprev + sigmoidf_(gi) * tanhf(gg);
  const float h1 = sigmoidf_(go) * tanhf(c1);
  out[OUT_H1 + nn * HH + h] = h1;
  out[OUT_C1 + nn * HH + h] = c1;
}

// ---------------- K7: predictions ----------------
__global__ __launch_bounds__(256) void pred_kernel(
    const float* __restrict__ Wc, const float* __restrict__ bc, float* out) {
  const int wid = blockIdx.x * 4 + (threadIdx.x >> 6);  // 0..319
  const int lane = threadIdx.x & 63;
  const int nn = wid / 10;
  const int c = wid % 10;
  const float* hp = out + OUT_H1 + (size_t)nn * HH;
  const float* wp = Wc + (size_t)c * HH;
  float p = 0.f;
#pragma unroll
  for (int j = 0; j < 8; ++j) p += hp[lane * 8 + j] * wp[lane * 8 + j];
  p = wave_reduce(p);
  if (lane == 0) out[OUT_PRED + nn * 10 + c] = p + bc[c];
}

extern "C" void kernel_launch(void* const* d_in, const int* in_sizes, int n_in,
                              void* d_out, int out_size, void* d_ws, size_t ws_size,
                              hipStream_t stream) {
  const int* x = (const int*)d_in[0];
  const float* enc = (const float*)d_in[1];
  const float* hidden = (const float*)d_in[2];
  const float* cell = (const float*)d_in[3];
  const float* We = (const float*)d_in[4];
  const float* be = (const float*)d_in[5];
  const float* emb = (const float*)d_in[6];
  const float* wih0 = (const float*)d_in[7];
  const float* whh0 = (const float*)d_in[8];
  const float* bih0 = (const float*)d_in[9];
  const float* bhh0 = (const float*)d_in[10];
  const float* wih1 = (const float*)d_in[11];
  const float* whh1 = (const float*)d_in[12];
  const float* bih1 = (const float*)d_in[13];
  const float* bhh1 = (const float*)d_in[14];
  const float* Wc = (const float*)d_in[15];
  const float* bc = (const float*)d_in[16];
  float* out = (float*)d_out;
  float* ws = (float*)d_ws;

  hipLaunchKernelGGL(attn_pass, dim3(1024), dim3(256), 0, stream, enc, hidden, We, be, ws);
  hipLaunchKernelGGL(reduce_ctx, dim3(256), dim3(256), 0, stream, x, emb, hidden, ws);
  hipLaunchKernelGGL(gates0_kernel, dim3(448), dim3(256), 0, stream, wih0, whh0, ws);
  hipLaunchKernelGGL(lstm0_kernel, dim3(64), dim3(256), 0, stream, cell, hidden, bih0, bhh0, out, ws);
  hipLaunchKernelGGL(gates1_kernel, dim3(512), dim3(256), 0, stream, wih1, whh1, ws);
  hipLaunchKernelGGL(lstm1_kernel, dim3(64), dim3(256), 0, stream, cell, bih1, bhh1, out, ws);
  hipLaunchKernelGGL(pred_kernel, dim3(80), dim3(256), 0, stream, Wc, bc, out);
}